// Round 2
// baseline (973.115 us; speedup 1.0000x reference)
//
#include <hip/hip_runtime.h>
#include <hip/hip_bf16.h>
#include <stdint.h>

#define T_ 2048
#define H_ 1024
#define I_ 2048
#define E_ 8
#define NE_ 9            // 8 routed + 1 shared (virtual expert)
#define BM 128
#define BK 32
#define BN 64
#define BKP 40           // padded k-stride (shorts) for transposed B tiles; 80B rows keep b128 alignment

typedef __attribute__((ext_vector_type(8))) short bf16x8;
typedef __attribute__((ext_vector_type(4))) float f32x4;

__device__ __forceinline__ unsigned short f2bf(float f) {
  unsigned int u; __builtin_memcpy(&u, &f, 4);
  u = (u + 0x7fffu + ((u >> 16) & 1u)) >> 16;
  return (unsigned short)u;
}

// pack 2 fp32 -> 2 bf16 (RNE) into dst[0],dst[1]
__device__ __forceinline__ void cvt2(float a, float b, unsigned short* dst) {
  __hip_bfloat162 h = __float22bfloat162_rn(float2{a, b});
  __builtin_memcpy(dst, &h, 4);
}

// ---------------- router: 1 wave per token, all fp32 ----------------
__global__ __launch_bounds__(256) void k_router(
    const float* __restrict__ x, const float* __restrict__ rw,
    float* zacc, float* pacc, int* cnt, int* topi, float* topw) {
  __shared__ float lds_rw[H_ * E_];  // 32 KB
  int tid = threadIdx.x;
#pragma unroll
  for (int i = 0; i < 8; i++)
    ((float4*)lds_rw)[i * 256 + tid] = ((const float4*)rw)[i * 256 + tid];
  __syncthreads();
  int wid = tid >> 6, lane = tid & 63;
  int t = blockIdx.x * 4 + wid;
  const float4* xv = (const float4*)(x + (size_t)t * H_ + lane * 16);
  float xr[16];
#pragma unroll
  for (int q = 0; q < 4; q++) {
    float4 v = xv[q];
    xr[q * 4] = v.x; xr[q * 4 + 1] = v.y; xr[q * 4 + 2] = v.z; xr[q * 4 + 3] = v.w;
  }
  float acc[E_];
#pragma unroll
  for (int e = 0; e < E_; e++) acc[e] = 0.f;
#pragma unroll
  for (int j = 0; j < 16; j++) {
    float xf = xr[j];
    const float* wrow = &lds_rw[(lane * 16 + j) * E_];
#pragma unroll
    for (int e = 0; e < E_; e++) acc[e] += xf * wrow[e];
  }
#pragma unroll
  for (int off = 32; off >= 1; off >>= 1) {
#pragma unroll
    for (int e = 0; e < E_; e++) acc[e] += __shfl_xor(acc[e], off, 64);
  }
  if (lane == 0) {
    float m = acc[0];
#pragma unroll
    for (int e = 1; e < E_; e++) m = fmaxf(m, acc[e]);
    float p[E_], s = 0.f;
#pragma unroll
    for (int e = 0; e < E_; e++) { p[e] = expf(acc[e] - m); s += p[e]; }
    float inv = 1.f / s;
#pragma unroll
    for (int e = 0; e < E_; e++) p[e] *= inv;
    float lse = m + logf(s);
    atomicAdd(zacc, lse * lse);
#pragma unroll
    for (int e = 0; e < E_; e++) atomicAdd(&pacc[e], p[e]);
    int i0 = 0;
#pragma unroll
    for (int e = 1; e < E_; e++) if (p[e] > p[i0]) i0 = e;
    int i1 = (i0 == 0) ? 1 : 0;
#pragma unroll
    for (int e = 0; e < E_; e++) if (e != i0 && e != i1 && p[e] > p[i1]) i1 = e;
    float w0 = p[i0], w1 = p[i1], wsum = w0 + w1;
    w0 /= wsum; w1 /= wsum;
    topi[t * 2] = i0; topi[t * 2 + 1] = i1;
    topw[t * 2] = w0; topw[t * 2 + 1] = w1;
    atomicAdd(&cnt[i0], 1); atomicAdd(&cnt[i1], 1);
  }
}

// ---------------- scan: offsets + aux loss (fp32 out) ----------------
__global__ void k_scan(const float* zacc, const float* pacc, int* cnt, int* offs,
                       float* out_aux) {
  if (threadIdx.x == 0 && blockIdx.x == 0) {
    cnt[E_] = T_;  // shared expert
    int o = 0;
    for (int e = 0; e < NE_; e++) { offs[e] = o; o += cnt[e]; }
    offs[NE_] = o;
    float lb = 0.f;
    for (int e = 0; e < E_; e++)
      lb += ((float)cnt[e] / 4096.f) * (pacc[e] / 2048.f);
    out_aux[0] = 0.01f * 8.f * lb + 0.001f * (zacc[0] / 2048.f);
  }
}

// ---------------- fill: compact expert token lists ----------------
__global__ __launch_bounds__(256) void k_fill(
    const int* __restrict__ topi, const float* __restrict__ topw,
    const int* __restrict__ offs, int* cur, int* tok, float* wgt) {
  int t = blockIdx.x * 256 + threadIdx.x;  // 0..2047
#pragma unroll
  for (int k = 0; k < 2; k++) {
    int e = topi[t * 2 + k];
    int pos = atomicAdd(&cur[e], 1);
    tok[offs[e] + pos] = t;
    wgt[offs[e] + pos] = topw[t * 2 + k];
  }
  tok[4096 + t] = t;  // shared expert identity (offs[8] == 4096 always)
  wgt[4096 + t] = 1.f;
}

// ---------------- GEMM1: h = silu(x*Wg) * (x*Wu), gathered rows ----------------
// grid: (mt=16, nt=I/BN, e=NE). x = mt so same-B blocks dispatch consecutively (L2 reuse).
__global__ __launch_bounds__(256) void k_gemm1(
    const float* __restrict__ x,
    const float* __restrict__ eg, const float* __restrict__ eu,
    const float* __restrict__ sg, const float* __restrict__ su,
    const int* __restrict__ cnt, const int* __restrict__ offs,
    const int* __restrict__ tok, unsigned short* __restrict__ hbuf) {
  int mt = blockIdx.x, nt = blockIdx.y, e = blockIdx.z;
  int cnt_e = cnt[e];
  if (mt * BM >= cnt_e) return;
  int offs_e = offs[e];
  const float* Bg = (e < E_) ? eg + (size_t)e * H_ * I_ : sg;
  const float* Bu = (e < E_) ? eu + (size_t)e * H_ * I_ : su;
  int n0 = nt * BN;

  __shared__ unsigned short As[BM * BK];       // row-major [m][k]
  __shared__ unsigned short BgS[BN * BKP];     // transposed [n][k], k-contiguous
  __shared__ unsigned short BuS[BN * BKP];

  int tid = threadIdx.x;
  // A staging: thread -> (row, 16-float half)
  int arow = tid >> 1, ahalf = tid & 1;
  int atok = tok[offs_e + min(mt * BM + arow, cnt_e - 1)];
  const float* aptr = x + (size_t)atok * H_ + ahalf * 16;
  // B staging: thread -> (n, k-group of 8)
  int bnn = tid & 63, bkg = (tid >> 6) * 8;
  const float* bgp = Bg + (size_t)bkg * I_ + n0 + bnn;
  const float* bup = Bu + (size_t)bkg * I_ + n0 + bnn;

  int lane = tid & 63, wid = tid >> 6;
  int quad = lane >> 4, l15 = lane & 15;
  int wm = wid >> 1, wn = wid & 1;

  f32x4 zero = {0.f, 0.f, 0.f, 0.f};
  f32x4 accg[4][2], accu[4][2];
#pragma unroll
  for (int mi = 0; mi < 4; mi++)
#pragma unroll
    for (int ni = 0; ni < 2; ni++) { accg[mi][ni] = zero; accu[mi][ni] = zero; }

  for (int k0 = 0; k0 < H_; k0 += BK) {
    // global loads (fp32)
    float4 av[4];
#pragma unroll
    for (int q = 0; q < 4; q++) av[q] = ((const float4*)(aptr + k0))[q];
    float bgv[8], buv[8];
#pragma unroll
    for (int j = 0; j < 8; j++) {
      bgv[j] = bgp[(size_t)(k0 + j) * I_];
      buv[j] = bup[(size_t)(k0 + j) * I_];
    }
    __syncthreads();
    // convert + stage
    {
      unsigned short tmp[16];
#pragma unroll
      for (int q = 0; q < 4; q++) {
        cvt2(av[q].x, av[q].y, &tmp[q * 4]);
        cvt2(av[q].z, av[q].w, &tmp[q * 4 + 2]);
      }
      bf16x8* dst = (bf16x8*)&As[arow * BK + ahalf * 16];
      dst[0] = *(bf16x8*)&tmp[0];
      dst[1] = *(bf16x8*)&tmp[8];
    }
    {
      unsigned short tg[8], tu[8];
#pragma unroll
      for (int j = 0; j < 4; j++) {
        cvt2(bgv[j * 2], bgv[j * 2 + 1], &tg[j * 2]);
        cvt2(buv[j * 2], buv[j * 2 + 1], &tu[j * 2]);
      }
      *(bf16x8*)&BgS[bnn * BKP + bkg] = *(bf16x8*)&tg[0];
      *(bf16x8*)&BuS[bnn * BKP + bkg] = *(bf16x8*)&tu[0];
    }
    __syncthreads();
    // fragments
    bf16x8 af[4];
#pragma unroll
    for (int mi = 0; mi < 4; mi++)
      af[mi] = *(const bf16x8*)&As[(wm * 64 + mi * 16 + l15) * BK + quad * 8];
#pragma unroll
    for (int ni = 0; ni < 2; ni++) {
      int n = wn * 32 + ni * 16 + l15;
      bf16x8 bg = *(const bf16x8*)&BgS[n * BKP + quad * 8];
      bf16x8 bu = *(const bf16x8*)&BuS[n * BKP + quad * 8];
#pragma unroll
      for (int mi = 0; mi < 4; mi++) {
        accg[mi][ni] = __builtin_amdgcn_mfma_f32_16x16x32_bf16(af[mi], bg, accg[mi][ni], 0, 0, 0);
        accu[mi][ni] = __builtin_amdgcn_mfma_f32_16x16x32_bf16(af[mi], bu, accu[mi][ni], 0, 0, 0);
      }
    }
  }
  // epilogue: h = silu(g)*u -> bf16 hbuf
#pragma unroll
  for (int mi = 0; mi < 4; mi++)
#pragma unroll
    for (int ni = 0; ni < 2; ni++) {
      int col = n0 + wn * 32 + ni * 16 + l15;
#pragma unroll
      for (int r = 0; r < 4; r++) {
        int row = mt * BM + wm * 64 + mi * 16 + quad * 4 + r;
        if (row < cnt_e) {
          float g = accg[mi][ni][r], u = accu[mi][ni][r];
          float sv = g / (1.f + __expf(-g));
          hbuf[(size_t)(offs_e + row) * I_ + col] = f2bf(sv * u);
        }
      }
    }
}

// ---------------- GEMM2: out += w * (h * Wd), fp32 atomic scatter ----------------
__global__ __launch_bounds__(256) void k_gemm2(
    const unsigned short* __restrict__ hbuf,
    const float* __restrict__ ed, const float* __restrict__ sd,
    const int* __restrict__ cnt, const int* __restrict__ offs,
    const int* __restrict__ tok, const float* __restrict__ wgt,
    float* __restrict__ out) {
  int mt = blockIdx.x, nt = blockIdx.y, e = blockIdx.z;
  int cnt_e = cnt[e];
  if (mt * BM >= cnt_e) return;
  int offs_e = offs[e];
  const float* Bd = (e < E_) ? ed + (size_t)e * I_ * H_ : sd;
  int n0 = nt * BN;

  __shared__ unsigned short As[BM * BK];
  __shared__ unsigned short BdS[BN * BKP];

  int tid = threadIdx.x;
  int arow = tid >> 1, ahalf = tid & 1;
  const unsigned short* aptr =
      hbuf + (size_t)(offs_e + min(mt * BM + arow, cnt_e - 1)) * I_ + ahalf * 16;
  int bnn = tid & 63, bkg = (tid >> 6) * 8;
  const float* bdp = Bd + (size_t)bkg * H_ + n0 + bnn;

  int lane = tid & 63, wid = tid >> 6;
  int quad = lane >> 4, l15 = lane & 15;
  int wm = wid >> 1, wn = wid & 1;

  f32x4 zero = {0.f, 0.f, 0.f, 0.f};
  f32x4 acc[4][2];
#pragma unroll
  for (int mi = 0; mi < 4; mi++)
#pragma unroll
    for (int ni = 0; ni < 2; ni++) acc[mi][ni] = zero;

  for (int k0 = 0; k0 < I_; k0 += BK) {
    bf16x8 av0 = ((const bf16x8*)(aptr + k0))[0];
    bf16x8 av1 = ((const bf16x8*)(aptr + k0))[1];
    float bdv[8];
#pragma unroll
    for (int j = 0; j < 8; j++) bdv[j] = bdp[(size_t)(k0 + j) * H_];
    __syncthreads();
    {
      bf16x8* dst = (bf16x8*)&As[arow * BK + ahalf * 16];
      dst[0] = av0; dst[1] = av1;
    }
    {
      unsigned short td[8];
#pragma unroll
      for (int j = 0; j < 4; j++) cvt2(bdv[j * 2], bdv[j * 2 + 1], &td[j * 2]);
      *(bf16x8*)&BdS[bnn * BKP + bkg] = *(bf16x8*)&td[0];
    }
    __syncthreads();
    bf16x8 af[4];
#pragma unroll
    for (int mi = 0; mi < 4; mi++)
      af[mi] = *(const bf16x8*)&As[(wm * 64 + mi * 16 + l15) * BK + quad * 8];
#pragma unroll
    for (int ni = 0; ni < 2; ni++) {
      int n = wn * 32 + ni * 16 + l15;
      bf16x8 bd = *(const bf16x8*)&BdS[n * BKP + quad * 8];
#pragma unroll
      for (int mi = 0; mi < 4; mi++)
        acc[mi][ni] = __builtin_amdgcn_mfma_f32_16x16x32_bf16(af[mi], bd, acc[mi][ni], 0, 0, 0);
    }
  }
  // epilogue: weighted fp32 atomic scatter into out
#pragma unroll
  for (int mi = 0; mi < 4; mi++)
#pragma unroll
    for (int r = 0; r < 4; r++) {
      int row = mt * BM + wm * 64 + mi * 16 + quad * 4 + r;
      if (row < cnt_e) {
        int tt = tok[offs_e + row];
        float w = wgt[offs_e + row];
#pragma unroll
        for (int ni = 0; ni < 2; ni++) {
          int col = n0 + wn * 32 + ni * 16 + l15;
          atomicAdd(&out[(size_t)tt * H_ + col], w * acc[mi][ni][r]);
        }
      }
    }
}

extern "C" void kernel_launch(void* const* d_in, const int* in_sizes, int n_in,
                              void* d_out, int out_size, void* d_ws, size_t ws_size,
                              hipStream_t stream) {
  const float* x  = (const float*)d_in[0];
  const float* rw = (const float*)d_in[1];
  const float* eg = (const float*)d_in[2];
  const float* eu = (const float*)d_in[3];
  const float* ed = (const float*)d_in[4];
  const float* sg = (const float*)d_in[5];
  const float* su = (const float*)d_in[6];
  const float* sd = (const float*)d_in[7];
  float* out = (float*)d_out;
  char* ws = (char*)d_ws;

  float* zacc = (float*)(ws + 0);
  float* pacc = (float*)(ws + 16);
  int*   cnt  = (int*)(ws + 64);
  int*   offs = (int*)(ws + 128);
  int*   cur  = (int*)(ws + 192);
  int*   topi = (int*)(ws + 512);
  float* topw = (float*)(ws + 512 + 16384);
  int*   tok  = (int*)(ws + 512 + 32768);
  float* wgt  = (float*)(ws + 512 + 32768 + 24576);
  unsigned short* hbuf = (unsigned short*)(ws + (1 << 20));  // 6144 x 2048 bf16 = 24 MB

  hipMemsetAsync(ws, 0, 512, stream);
  hipMemsetAsync(out, 0, (size_t)T_ * H_ * 4, stream);  // atomics accumulate into out
  k_router<<<512, 256, 0, stream>>>(x, rw, zacc, pacc, cnt, topi, topw);
  k_scan<<<1, 64, 0, stream>>>(zacc, pacc, cnt, offs, out + (size_t)T_ * H_);
  k_fill<<<8, 256, 0, stream>>>(topi, topw, offs, cur, tok, wgt);
  dim3 g1(16, I_ / BN, NE_);
  k_gemm1<<<g1, 256, 0, stream>>>(x, eg, eu, sg, su, cnt, offs, tok, hbuf);
  dim3 g2(16, H_ / BN, NE_);
  k_gemm2<<<g2, 256, 0, stream>>>(hbuf, ed, sd, cnt, offs, tok, wgt, out);
}